// Round 3
// baseline (1149.078 us; speedup 1.0000x reference)
//
#include <hip/hip_runtime.h>
#include <cstdint>

#define C_DIM 256
#define EPS 1e-5f

typedef __attribute__((ext_vector_type(8))) short short8;
typedef __attribute__((ext_vector_type(4))) float f32x4;

__device__ __forceinline__ ushort f2bf(float f) {
  uint32_t u = __float_as_uint(f);
  u = (u + 0x7fffu + ((u >> 16) & 1u)) >> 16;
  return (ushort)u;
}
__device__ __forceinline__ float bflo(uint32_t p) { return __uint_as_float(p << 16); }
__device__ __forceinline__ float bfhi(uint32_t p) { return __uint_as_float(p & 0xffff0000u); }

// ---------------- setup kernels ----------------
__global__ void k_count(const int* __restrict__ col, int E, int* cnt) {
  int e = blockIdx.x * blockDim.x + threadIdx.x;
  if (e < E) atomicAdd(&cnt[col[e]], 1);
}

__global__ void k_isd(int* cnt, float* isd, int n) {
  int i = blockIdx.x * blockDim.x + threadIdx.x;
  if (i < n) { isd[i] = rsqrtf((float)(cnt[i] + 1)); cnt[i] = 0; }
}

__global__ void k_scan1(const int* __restrict__ cnt, int* excl, int* bsum, int n) {
  __shared__ int s[1024];
  int i = blockIdx.x * 1024 + threadIdx.x;
  int v = (i < n) ? cnt[i] : 0;
  s[threadIdx.x] = v;
  __syncthreads();
  for (int off = 1; off < 1024; off <<= 1) {
    int t = (threadIdx.x >= off) ? s[threadIdx.x - off] : 0;
    __syncthreads();
    s[threadIdx.x] += t;
    __syncthreads();
  }
  if (i < n) excl[i] = s[threadIdx.x] - v;
  if (threadIdx.x == 1023) bsum[blockIdx.x] = s[1023];
}

__global__ void k_scan2(int* bsum, int nb) {
  __shared__ int s[1024];
  int v = (threadIdx.x < nb) ? bsum[threadIdx.x] : 0;
  s[threadIdx.x] = v;
  __syncthreads();
  for (int off = 1; off < 1024; off <<= 1) {
    int t = (threadIdx.x >= off) ? s[threadIdx.x - off] : 0;
    __syncthreads();
    s[threadIdx.x] += t;
    __syncthreads();
  }
  if (threadIdx.x < nb) bsum[threadIdx.x] = s[threadIdx.x] - v;
}

__global__ void k_scan3(int* excl, const int* __restrict__ bsum, int n, int E) {
  int i = blockIdx.x * 1024 + threadIdx.x;
  if (i < n) excl[i] += bsum[blockIdx.x];
  if (i == 0) excl[n] = E;
}

// CSR fill: only the source index (norm recomputed from L2-resident isd)
__global__ void k_fill(const int* __restrict__ row, const int* __restrict__ col, int E,
                       const int* __restrict__ row_ptr, int* cursor,
                       int* __restrict__ es) {
  int e = blockIdx.x * blockDim.x + threadIdx.x;
  if (e < E) {
    int d = col[e], s = row[e];
    int p = row_ptr[d] + atomicAdd(&cursor[d], 1);
    es[p] = s;
  }
}

__global__ void k_cvt_x(const float* __restrict__ x, ushort* __restrict__ xb, int n4) {
  int i = blockIdx.x * blockDim.x + threadIdx.x;
  if (i < n4) {
    float4 v = ((const float4*)x)[i];
    ushort4 o;
    o.x = f2bf(v.x); o.y = f2bf(v.y); o.z = f2bf(v.z); o.w = f2bf(v.w);
    ((ushort4*)xb)[i] = o;
  }
}

__global__ void k_cvt_w(const float* __restrict__ W1, const float* __restrict__ W2,
                        ushort* __restrict__ Wt1, ushort* __restrict__ Wt2) {
  int i = blockIdx.x * blockDim.x + threadIdx.x;
  int n = i >> 8, k = i & 255;
  Wt1[i] = f2bf(W1[k * 256 + n]);
  Wt2[i] = f2bf(W2[k * 256 + n]);
}

// ---------------- bf16 MFMA GEMM (round-0 proven) with CHUNKED output ----------------
// Cc[g][node][16ch] bf16, g = col>>4 : the layout k_agg_x gathers from.
__global__ __launch_bounds__(256) void k_gemm_bf16(const ushort* __restrict__ A,
                                                   const ushort* __restrict__ Wt,
                                                   ushort* __restrict__ Cc, int M) {
  __shared__ ushort As[128 * 64];
  __shared__ ushort Bs[128 * 64];
  const int tid = threadIdx.x;
  const int wave = tid >> 6, lane = tid & 63;
  const int bm = blockIdx.x * 128;
  const int bn = blockIdx.y * 128;
  const int wm = (wave >> 1) * 64, wn = (wave & 1) * 64;

  f32x4 acc[4][4] = {};

  const int r_off = lane >> 3;  // 0..7 rows per 1KB staging inst
  const int cc = lane & 7;      // 16B chunk slot within row

  for (int k0 = 0; k0 < C_DIM; k0 += 64) {
#pragma unroll
    for (int j = 0; j < 4; j++) {
      int rl = wave * 32 + j * 8 + r_off;  // tile row 0..127
      int c = cc ^ (rl & 7);               // swizzled source chunk
      int gm = bm + rl; if (gm >= M) gm = M - 1;
      const ushort* ga = &A[(size_t)gm * C_DIM + k0 + c * 8];
      ushort* la = &As[(size_t)(wave * 32 + j * 8) * 64];
      __builtin_amdgcn_global_load_lds((const __attribute__((address_space(1))) void*)ga,
                                       (__attribute__((address_space(3))) void*)la, 16, 0, 0);
      const ushort* gb = &Wt[(size_t)(bn + rl) * C_DIM + k0 + c * 8];
      ushort* lb = &Bs[(size_t)(wave * 32 + j * 8) * 64];
      __builtin_amdgcn_global_load_lds((const __attribute__((address_space(1))) void*)gb,
                                       (__attribute__((address_space(3))) void*)lb, 16, 0, 0);
    }
    __syncthreads();
#pragma unroll
    for (int s = 0; s < 2; s++) {
      short8 af[4], bfr[4];
#pragma unroll
      for (int t = 0; t < 4; t++) {
        int ra = wm + t * 16 + (lane & 15);
        int ca = s * 4 + (lane >> 4);
        af[t] = *(const short8*)&As[ra * 64 + ((ca ^ (ra & 7)) << 3)];
        int rb = wn + t * 16 + (lane & 15);
        bfr[t] = *(const short8*)&Bs[rb * 64 + ((ca ^ (rb & 7)) << 3)];
      }
#pragma unroll
      for (int mt = 0; mt < 4; mt++)
#pragma unroll
        for (int nt = 0; nt < 4; nt++)
          acc[mt][nt] = __builtin_amdgcn_mfma_f32_16x16x32_bf16(af[mt], bfr[nt], acc[mt][nt], 0, 0, 0);
    }
    __syncthreads();
  }

  // epilogue: C/D layout col=lane&15, row=(lane>>4)*4+reg (m89-verified)
  // chunked store: channel col -> slab col>>4, intra-offset col&15 (= lane&15)
#pragma unroll
  for (int mt = 0; mt < 4; mt++) {
#pragma unroll
    for (int nt = 0; nt < 4; nt++) {
      int slab = (bn + wn) / 16 + nt;
      int row0 = bm + wm + mt * 16 + ((lane >> 4) << 2);
#pragma unroll
      for (int r = 0; r < 4; r++) {
        int row = row0 + r;
        if (row < M) Cc[((size_t)slab * M + row) * 16 + (lane & 15)] = f2bf(acc[mt][nt][r]);
      }
    }
  }
}

// ---------------- XCD-pinned chunked gather-aggregate ----------------
// XCD x (= blockIdx%8) owns channels [32x, 32x+32) for ALL nodes, processed as two
// 16-channel half-passes whose 3.2MB table slice stays resident in that XCD's 4MB L2.
__global__ __launch_bounds__(256) void k_agg_x(const ushort* __restrict__ xwc,
    const int* __restrict__ es, const int* __restrict__ row_ptr,
    const float* __restrict__ isd, ushort* __restrict__ axc, int n) {
  const int xcd = blockIdx.x & 7;
  const int sub = blockIdx.x >> 3;       // 0..255
  const int NB = (n + 255) >> 8;
  int base = sub * NB;
  int end = base + NB; if (end > n) end = n;
  const int grp = threadIdx.x >> 2;      // 64 groups of 4 lanes per block
  const int cl = threadIdx.x & 3;        // 8B sub-chunk (4 channels) within 32B

#pragma unroll
  for (int h = 0; h < 2; h++) {
    const int g = xcd * 2 + h;           // global 16-channel slab id
    const ushort* slab = xwc + (size_t)g * n * 16;
    ushort* oslab = axc + (size_t)g * n * 16;

    for (int i = base + grp; i < end; i += 64) {
      float si = isd[i];
      float sn = si * si;
      uint2 p = *(const uint2*)&slab[(size_t)i * 16 + cl * 4];
      float a0 = bflo(p.x) * sn, a1 = bfhi(p.x) * sn;
      float a2 = bflo(p.y) * sn, a3 = bfhi(p.y) * sn;

      int e1 = row_ptr[i + 1];
      int e = row_ptr[i];
      for (; e + 3 < e1; e += 4) {
        int s0 = es[e], s1 = es[e + 1], s2 = es[e + 2], s3 = es[e + 3];
        uint2 v0 = *(const uint2*)&slab[(size_t)s0 * 16 + cl * 4];
        uint2 v1 = *(const uint2*)&slab[(size_t)s1 * 16 + cl * 4];
        uint2 v2 = *(const uint2*)&slab[(size_t)s2 * 16 + cl * 4];
        uint2 v3 = *(const uint2*)&slab[(size_t)s3 * 16 + cl * 4];
        float w0 = isd[s0] * si, w1 = isd[s1] * si;
        float w2 = isd[s2] * si, w3 = isd[s3] * si;
        a0 += bflo(v0.x) * w0 + bflo(v1.x) * w1 + bflo(v2.x) * w2 + bflo(v3.x) * w3;
        a1 += bfhi(v0.x) * w0 + bfhi(v1.x) * w1 + bfhi(v2.x) * w2 + bfhi(v3.x) * w3;
        a2 += bflo(v0.y) * w0 + bflo(v1.y) * w1 + bflo(v2.y) * w2 + bflo(v3.y) * w3;
        a3 += bfhi(v0.y) * w0 + bfhi(v1.y) * w1 + bfhi(v2.y) * w2 + bfhi(v3.y) * w3;
      }
      for (; e < e1; e++) {
        int s0 = es[e];
        float w0 = isd[s0] * si;
        uint2 v0 = *(const uint2*)&slab[(size_t)s0 * 16 + cl * 4];
        a0 += bflo(v0.x) * w0; a1 += bfhi(v0.x) * w0;
        a2 += bflo(v0.y) * w0; a3 += bfhi(v0.y) * w0;
      }

      uint2 q;
      q.x = (uint32_t)f2bf(a0) | ((uint32_t)f2bf(a1) << 16);
      q.y = (uint32_t)f2bf(a2) | ((uint32_t)f2bf(a3) << 16);
      *(uint2*)&oslab[(size_t)i * 16 + cl * 4] = q;
    }
  }
}

// ---------------- bias + LayerNorm + ReLU (streaming, reads chunked agg) ----------------
__global__ __launch_bounds__(256) void k_ln(const ushort* __restrict__ axc,
    const float* __restrict__ bias, const float* __restrict__ gamma,
    const float* __restrict__ beta, float* __restrict__ out,
    ushort* __restrict__ outb, int n) {
  int i = blockIdx.x * 4 + (threadIdx.x >> 6);
  int lane = threadIdx.x & 63;
  if (i >= n) return;

  // lane covers channels [4*lane, 4*lane+4): slab = lane>>2, intra = (lane&3)*4
  uint2 p = *(const uint2*)&axc[((size_t)(lane >> 2) * n + i) * 16 + (lane & 3) * 4];
  float4 bv = ((const float4*)bias)[lane];
  float a0 = bflo(p.x) + bv.x, a1 = bfhi(p.x) + bv.y;
  float a2 = bflo(p.y) + bv.z, a3 = bfhi(p.y) + bv.w;

  float sum = a0 + a1 + a2 + a3;
  float sq = a0 * a0 + a1 * a1 + a2 * a2 + a3 * a3;
#pragma unroll
  for (int off = 32; off >= 1; off >>= 1) {
    sum += __shfl_xor(sum, off, 64);
    sq += __shfl_xor(sq, off, 64);
  }
  float mu = sum * (1.0f / C_DIM);
  float var = sq * (1.0f / C_DIM) - mu * mu;
  float rs = rsqrtf(var + EPS);

  float4 g = ((const float4*)gamma)[lane];
  float4 bt = ((const float4*)beta)[lane];
  f32x4 o;
  o[0] = fmaxf((a0 - mu) * rs * g.x + bt.x, 0.0f);
  o[1] = fmaxf((a1 - mu) * rs * g.y + bt.y, 0.0f);
  o[2] = fmaxf((a2 - mu) * rs * g.z + bt.z, 0.0f);
  o[3] = fmaxf((a3 - mu) * rs * g.w + bt.w, 0.0f);
  // final output, never re-read on-device (clang ext_vector is valid for nontemporal)
  __builtin_nontemporal_store(o, (f32x4*)&((float*)out)[((size_t)i * 64 + lane) * 4]);

  if (outb) {  // node-major bf16 feeding the next GEMM
    uint2 q;
    q.x = (uint32_t)f2bf(o[0]) | ((uint32_t)f2bf(o[1]) << 16);
    q.y = (uint32_t)f2bf(o[2]) | ((uint32_t)f2bf(o[3]) << 16);
    ((uint2*)outb)[(size_t)i * 64 + lane] = q;
  }
}

// ---------------- host ----------------
extern "C" void kernel_launch(void* const* d_in, const int* in_sizes, int n_in,
                              void* d_out, int out_size, void* d_ws, size_t ws_size,
                              hipStream_t stream) {
  const float* x = (const float*)d_in[0];
  const int* edges = (const int*)d_in[1];
  const float* W1 = (const float*)d_in[2];
  const float* b1 = (const float*)d_in[3];
  const float* W2 = (const float*)d_in[4];
  const float* b2 = (const float*)d_in[5];
  const float* gamma = (const float*)d_in[6];
  const float* beta = (const float*)d_in[7];

  int N = in_sizes[0] / C_DIM;
  int E = in_sizes[1] / 2;
  const int* row = edges;
  const int* col = edges + E;

  char* ws = (char*)d_ws;
  size_t off = 0;
  auto alloc = [&](size_t bytes) -> void* {
    void* p = ws + off;
    off = (off + bytes + 255) & ~(size_t)255;
    return p;
  };
  ushort* xb  = (ushort*)alloc((size_t)N * C_DIM * 2);  // node-major bf16 (x, later z1)
  ushort* xwc = (ushort*)alloc((size_t)N * C_DIM * 2);  // chunked GEMM output [g][node][16]
  ushort* axc = (ushort*)alloc((size_t)N * C_DIM * 2);  // chunked agg output
  ushort* Wt1 = (ushort*)alloc(65536 * 2);
  ushort* Wt2 = (ushort*)alloc(65536 * 2);
  int* cnt = (int*)alloc((size_t)N * 4);                 // reused as fill cursor
  float* isd = (float*)alloc((size_t)N * 4);
  int* row_ptr = (int*)alloc((size_t)(N + 1) * 4);
  int nb = (N + 1023) / 1024;
  int* bsum = (int*)alloc((size_t)nb * 4);
  int* es = (int*)alloc((size_t)E * 4);                  // CSR-ordered sources

  float* z1 = (float*)d_out;
  float* z2 = (float*)d_out + (size_t)N * C_DIM;

  // conversions
  int n4 = N * C_DIM / 4;
  k_cvt_x<<<(n4 + 255) / 256, 256, 0, stream>>>(x, xb, n4);
  k_cvt_w<<<256, 256, 0, stream>>>(W1, W2, Wt1, Wt2);

  // CSR build (shared by both layers)
  (void)hipMemsetAsync(cnt, 0, (size_t)N * 4, stream);
  k_count<<<(E + 255) / 256, 256, 0, stream>>>(col, E, cnt);
  k_scan1<<<nb, 1024, 0, stream>>>(cnt, row_ptr, bsum, N);
  k_scan2<<<1, 1024, 0, stream>>>(bsum, nb);
  k_scan3<<<nb, 1024, 0, stream>>>(row_ptr, bsum, N, E);
  k_isd<<<(N + 255) / 256, 256, 0, stream>>>(cnt, isd, N);  // zeroes cnt -> cursor
  k_fill<<<(E + 255) / 256, 256, 0, stream>>>(row, col, E, row_ptr, cnt, es);

  dim3 ggrid((N + 127) / 128, 2);
  int ln_blocks = (N + 3) / 4;

  // layer 1
  k_gemm_bf16<<<ggrid, 256, 0, stream>>>(xb, Wt1, xwc, N);
  k_agg_x<<<2048, 256, 0, stream>>>(xwc, es, row_ptr, isd, axc, N);
  k_ln<<<ln_blocks, 256, 0, stream>>>(axc, b1, gamma, beta, z1, xb, N);
  // layer 2 (xb now holds z1 in bf16)
  k_gemm_bf16<<<ggrid, 256, 0, stream>>>(xb, Wt2, xwc, N);
  k_agg_x<<<2048, 256, 0, stream>>>(xwc, es, row_ptr, isd, axc, N);
  k_ln<<<ln_blocks, 256, 0, stream>>>(axc, b2, gamma, beta, z2, nullptr, N);
}

// Round 4
// 730.742 us; speedup vs baseline: 1.5725x; 1.5725x over previous
//
#include <hip/hip_runtime.h>
#include <cstdint>

#define C_DIM 256
#define EPS 1e-5f

typedef __attribute__((ext_vector_type(8))) short short8;
typedef __attribute__((ext_vector_type(4))) float f32x4;

__device__ __forceinline__ ushort f2bf(float f) {
  uint32_t u = __float_as_uint(f);
  u = (u + 0x7fffu + ((u >> 16) & 1u)) >> 16;
  return (ushort)u;
}
__device__ __forceinline__ float bflo(uint32_t p) { return __uint_as_float(p << 16); }
__device__ __forceinline__ float bfhi(uint32_t p) { return __uint_as_float(p & 0xffff0000u); }

// ---------------- setup kernels ----------------
__global__ void k_count(const int* __restrict__ col, int E, int* cnt) {
  int e = blockIdx.x * blockDim.x + threadIdx.x;
  if (e < E) atomicAdd(&cnt[col[e]], 1);
}

// reads cnt -> isd, then zeroes cnt so it can be reused as the fill cursor
__global__ void k_isd(int* cnt, float* isd, int n) {
  int i = blockIdx.x * blockDim.x + threadIdx.x;
  if (i < n) { isd[i] = rsqrtf((float)(cnt[i] + 1)); cnt[i] = 0; }
}

__global__ void k_scan1(const int* __restrict__ cnt, int* excl, int* bsum, int n) {
  __shared__ int s[1024];
  int i = blockIdx.x * 1024 + threadIdx.x;
  int v = (i < n) ? cnt[i] : 0;
  s[threadIdx.x] = v;
  __syncthreads();
  for (int off = 1; off < 1024; off <<= 1) {
    int t = (threadIdx.x >= off) ? s[threadIdx.x - off] : 0;
    __syncthreads();
    s[threadIdx.x] += t;
    __syncthreads();
  }
  if (i < n) excl[i] = s[threadIdx.x] - v;
  if (threadIdx.x == 1023) bsum[blockIdx.x] = s[1023];
}

__global__ void k_scan2(int* bsum, int nb) {
  __shared__ int s[1024];
  int v = (threadIdx.x < nb) ? bsum[threadIdx.x] : 0;
  s[threadIdx.x] = v;
  __syncthreads();
  for (int off = 1; off < 1024; off <<= 1) {
    int t = (threadIdx.x >= off) ? s[threadIdx.x - off] : 0;
    __syncthreads();
    s[threadIdx.x] += t;
    __syncthreads();
  }
  if (threadIdx.x < nb) bsum[threadIdx.x] = s[threadIdx.x] - v;
}

__global__ void k_scan3(int* excl, const int* __restrict__ bsum, int n, int E) {
  int i = blockIdx.x * 1024 + threadIdx.x;
  if (i < n) excl[i] += bsum[blockIdx.x];
  if (i == 0) excl[n] = E;
}

// packed edge record: .x = src node, .y = fp32 bits of norm
__global__ void k_fill(const int* __restrict__ row, const int* __restrict__ col, int E,
                       const int* __restrict__ row_ptr, int* cursor,
                       const float* __restrict__ isd, int2* __restrict__ edat) {
  int e = blockIdx.x * blockDim.x + threadIdx.x;
  if (e < E) {
    int d = col[e], s = row[e];
    int p = row_ptr[d] + atomicAdd(&cursor[d], 1);
    edat[p] = make_int2(s, __float_as_int(isd[s] * isd[d]));
  }
}

__global__ void k_cvt_x(const float* __restrict__ x, ushort* __restrict__ xb, int n4) {
  int i = blockIdx.x * blockDim.x + threadIdx.x;
  if (i < n4) {
    float4 v = ((const float4*)x)[i];
    ushort4 o;
    o.x = f2bf(v.x); o.y = f2bf(v.y); o.z = f2bf(v.z); o.w = f2bf(v.w);
    ((ushort4*)xb)[i] = o;
  }
}

// W [K][N] fp32 -> Wt [N][K] bf16, for both layer weights
__global__ void k_cvt_w(const float* __restrict__ W1, const float* __restrict__ W2,
                        ushort* __restrict__ Wt1, ushort* __restrict__ Wt2) {
  int i = blockIdx.x * blockDim.x + threadIdx.x;  // output index [n][k]
  int n = i >> 8, k = i & 255;
  Wt1[i] = f2bf(W1[k * 256 + n]);
  Wt2[i] = f2bf(W2[k * 256 + n]);
}

// ---------------- bf16 MFMA GEMM: Cb[M,256] = A[M,256] @ Wt^T ----------------
__global__ __launch_bounds__(256) void k_gemm_bf16(const ushort* __restrict__ A,
                                                   const ushort* __restrict__ Wt,
                                                   ushort* __restrict__ Cb, int M) {
  __shared__ ushort As[128 * 64];
  __shared__ ushort Bs[128 * 64];
  const int tid = threadIdx.x;
  const int wave = tid >> 6, lane = tid & 63;
  const int bm = blockIdx.x * 128;
  const int bn = blockIdx.y * 128;
  const int wm = (wave >> 1) * 64, wn = (wave & 1) * 64;

  f32x4 acc[4][4] = {};

  const int r_off = lane >> 3;  // 0..7 rows per 1KB staging inst
  const int cc = lane & 7;      // 16B chunk slot within row

  for (int k0 = 0; k0 < C_DIM; k0 += 64) {
#pragma unroll
    for (int j = 0; j < 4; j++) {
      int rl = wave * 32 + j * 8 + r_off;  // tile row 0..127
      int c = cc ^ (rl & 7);               // swizzled source chunk
      int gm = bm + rl; if (gm >= M) gm = M - 1;
      const ushort* ga = &A[(size_t)gm * C_DIM + k0 + c * 8];
      ushort* la = &As[(size_t)(wave * 32 + j * 8) * 64];
      __builtin_amdgcn_global_load_lds((const __attribute__((address_space(1))) void*)ga,
                                       (__attribute__((address_space(3))) void*)la, 16, 0, 0);
      const ushort* gb = &Wt[(size_t)(bn + rl) * C_DIM + k0 + c * 8];
      ushort* lb = &Bs[(size_t)(wave * 32 + j * 8) * 64];
      __builtin_amdgcn_global_load_lds((const __attribute__((address_space(1))) void*)gb,
                                       (__attribute__((address_space(3))) void*)lb, 16, 0, 0);
    }
    __syncthreads();
#pragma unroll
    for (int s = 0; s < 2; s++) {
      short8 af[4], bfr[4];
#pragma unroll
      for (int t = 0; t < 4; t++) {
        int ra = wm + t * 16 + (lane & 15);
        int ca = s * 4 + (lane >> 4);
        af[t] = *(const short8*)&As[ra * 64 + ((ca ^ (ra & 7)) << 3)];
        int rb = wn + t * 16 + (lane & 15);
        bfr[t] = *(const short8*)&Bs[rb * 64 + ((ca ^ (rb & 7)) << 3)];
      }
#pragma unroll
      for (int mt = 0; mt < 4; mt++)
#pragma unroll
        for (int nt = 0; nt < 4; nt++)
          acc[mt][nt] = __builtin_amdgcn_mfma_f32_16x16x32_bf16(af[mt], bfr[nt], acc[mt][nt], 0, 0, 0);
    }
    __syncthreads();
  }

  // epilogue: C/D layout col=lane&15, row=(lane>>4)*4+reg (m89-verified)
#pragma unroll
  for (int mt = 0; mt < 4; mt++) {
#pragma unroll
    for (int nt = 0; nt < 4; nt++) {
      int col = bn + wn + nt * 16 + (lane & 15);
      int row0 = bm + wm + mt * 16 + ((lane >> 4) << 2);
#pragma unroll
      for (int r = 0; r < 4; r++) {
        int row = row0 + r;
        if (row < M) Cb[(size_t)row * C_DIM + col] = f2bf(acc[mt][nt][r]);
      }
    }
  }
}

// ---------------- fused aggregate(bf16 gather) + bias + LN + ReLU ----------------
// 8-deep gather pipeline: 8 independent 512B row-reads in flight per wave.
__global__ __launch_bounds__(256) void k_agg_ln(const ushort* __restrict__ xwb,
    const int2* __restrict__ edat, const int* __restrict__ row_ptr,
    const float* __restrict__ isd,
    const float* __restrict__ bias, const float* __restrict__ gamma,
    const float* __restrict__ beta, float* __restrict__ out,
    ushort* __restrict__ outb, int n) {
  int i = blockIdx.x * 4 + (threadIdx.x >> 6);
  int lane = threadIdx.x & 63;
  if (i >= n) return;
  const uint2* xw2 = (const uint2*)xwb;  // 8B = 4 bf16 channels per lane

  float si = isd[i];
  float sn = si * si;
  uint2 p = xw2[(size_t)i * 64 + lane];
  float a0 = bflo(p.x) * sn, a1 = bfhi(p.x) * sn;
  float a2 = bflo(p.y) * sn, a3 = bfhi(p.y) * sn;

  int e0 = row_ptr[i], e1 = row_ptr[i + 1];
  int e = e0;
  // 8-deep: 8 independent row-gathers in flight per wave (latency-regime probe/fix)
  for (; e + 7 < e1; e += 8) {
    int2 ed0 = edat[e],     ed1 = edat[e + 1], ed2 = edat[e + 2], ed3 = edat[e + 3];
    int2 ed4 = edat[e + 4], ed5 = edat[e + 5], ed6 = edat[e + 6], ed7 = edat[e + 7];
    uint2 v0 = xw2[(size_t)ed0.x * 64 + lane];
    uint2 v1 = xw2[(size_t)ed1.x * 64 + lane];
    uint2 v2 = xw2[(size_t)ed2.x * 64 + lane];
    uint2 v3 = xw2[(size_t)ed3.x * 64 + lane];
    uint2 v4 = xw2[(size_t)ed4.x * 64 + lane];
    uint2 v5 = xw2[(size_t)ed5.x * 64 + lane];
    uint2 v6 = xw2[(size_t)ed6.x * 64 + lane];
    uint2 v7 = xw2[(size_t)ed7.x * 64 + lane];
    float w0 = __int_as_float(ed0.y), w1 = __int_as_float(ed1.y);
    float w2 = __int_as_float(ed2.y), w3 = __int_as_float(ed3.y);
    float w4 = __int_as_float(ed4.y), w5 = __int_as_float(ed5.y);
    float w6 = __int_as_float(ed6.y), w7 = __int_as_float(ed7.y);
    a0 += bflo(v0.x) * w0 + bflo(v1.x) * w1 + bflo(v2.x) * w2 + bflo(v3.x) * w3
        + bflo(v4.x) * w4 + bflo(v5.x) * w5 + bflo(v6.x) * w6 + bflo(v7.x) * w7;
    a1 += bfhi(v0.x) * w0 + bfhi(v1.x) * w1 + bfhi(v2.x) * w2 + bfhi(v3.x) * w3
        + bfhi(v4.x) * w4 + bfhi(v5.x) * w5 + bfhi(v6.x) * w6 + bfhi(v7.x) * w7;
    a2 += bflo(v0.y) * w0 + bflo(v1.y) * w1 + bflo(v2.y) * w2 + bflo(v3.y) * w3
        + bflo(v4.y) * w4 + bflo(v5.y) * w5 + bflo(v6.y) * w6 + bflo(v7.y) * w7;
    a3 += bfhi(v0.y) * w0 + bfhi(v1.y) * w1 + bfhi(v2.y) * w2 + bfhi(v3.y) * w3
        + bfhi(v4.y) * w4 + bfhi(v5.y) * w5 + bfhi(v6.y) * w6 + bfhi(v7.y) * w7;
  }
  for (; e + 3 < e1; e += 4) {
    int2 ed0 = edat[e], ed1 = edat[e + 1], ed2 = edat[e + 2], ed3 = edat[e + 3];
    uint2 v0 = xw2[(size_t)ed0.x * 64 + lane];
    uint2 v1 = xw2[(size_t)ed1.x * 64 + lane];
    uint2 v2 = xw2[(size_t)ed2.x * 64 + lane];
    uint2 v3 = xw2[(size_t)ed3.x * 64 + lane];
    float w0 = __int_as_float(ed0.y), w1 = __int_as_float(ed1.y);
    float w2 = __int_as_float(ed2.y), w3 = __int_as_float(ed3.y);
    a0 += bflo(v0.x) * w0 + bflo(v1.x) * w1 + bflo(v2.x) * w2 + bflo(v3.x) * w3;
    a1 += bfhi(v0.x) * w0 + bfhi(v1.x) * w1 + bfhi(v2.x) * w2 + bfhi(v3.x) * w3;
    a2 += bflo(v0.y) * w0 + bflo(v1.y) * w1 + bflo(v2.y) * w2 + bflo(v3.y) * w3;
    a3 += bfhi(v0.y) * w0 + bfhi(v1.y) * w1 + bfhi(v2.y) * w2 + bfhi(v3.y) * w3;
  }
  for (; e < e1; e++) {
    int2 ed = edat[e];
    float w0 = __int_as_float(ed.y);
    uint2 v0 = xw2[(size_t)ed.x * 64 + lane];
    a0 += bflo(v0.x) * w0; a1 += bfhi(v0.x) * w0;
    a2 += bflo(v0.y) * w0; a3 += bfhi(v0.y) * w0;
  }

  float4 bv = ((const float4*)bias)[lane];
  a0 += bv.x; a1 += bv.y; a2 += bv.z; a3 += bv.w;

  float sum = a0 + a1 + a2 + a3;
  float sq = a0 * a0 + a1 * a1 + a2 * a2 + a3 * a3;
#pragma unroll
  for (int off = 32; off >= 1; off >>= 1) {
    sum += __shfl_xor(sum, off, 64);
    sq += __shfl_xor(sq, off, 64);
  }
  float mu = sum * (1.0f / C_DIM);
  float var = sq * (1.0f / C_DIM) - mu * mu;
  float rs = rsqrtf(var + EPS);

  float4 g = ((const float4*)gamma)[lane];
  float4 bt = ((const float4*)beta)[lane];
  f32x4 o;
  o[0] = fmaxf((a0 - mu) * rs * g.x + bt.x, 0.0f);
  o[1] = fmaxf((a1 - mu) * rs * g.y + bt.y, 0.0f);
  o[2] = fmaxf((a2 - mu) * rs * g.z + bt.z, 0.0f);
  o[3] = fmaxf((a3 - mu) * rs * g.w + bt.w, 0.0f);
  // final fp32 output is never re-read on-device: nontemporal keeps it out of L2
  // so gather-table lines survive (write traffic stops evicting them)
  __builtin_nontemporal_store(o, (f32x4*)&out[((size_t)i * 64 + lane) * 4]);

  if (outb) {  // bf16 copy feeding next layer's GEMM
    uint2 q;
    q.x = (uint32_t)f2bf(o[0]) | ((uint32_t)f2bf(o[1]) << 16);
    q.y = (uint32_t)f2bf(o[2]) | ((uint32_t)f2bf(o[3]) << 16);
    ((uint2*)outb)[(size_t)i * 64 + lane] = q;
  }
}

// ---------------- host ----------------
extern "C" void kernel_launch(void* const* d_in, const int* in_sizes, int n_in,
                              void* d_out, int out_size, void* d_ws, size_t ws_size,
                              hipStream_t stream) {
  const float* x = (const float*)d_in[0];
  const int* edges = (const int*)d_in[1];
  const float* W1 = (const float*)d_in[2];
  const float* b1 = (const float*)d_in[3];
  const float* W2 = (const float*)d_in[4];
  const float* b2 = (const float*)d_in[5];
  const float* gamma = (const float*)d_in[6];
  const float* beta = (const float*)d_in[7];

  int N = in_sizes[0] / C_DIM;
  int E = in_sizes[1] / 2;
  const int* row = edges;
  const int* col = edges + E;

  char* ws = (char*)d_ws;
  size_t off = 0;
  auto alloc = [&](size_t bytes) -> void* {
    void* p = ws + off;
    off = (off + bytes + 255) & ~(size_t)255;
    return p;
  };
  ushort* xwb = (ushort*)alloc((size_t)N * C_DIM * 2);  // GEMM output, bf16
  ushort* xb  = (ushort*)alloc((size_t)N * C_DIM * 2);  // layer-1 A; aliased as z1-bf16 after agg1
  ushort* Wt1 = (ushort*)alloc(65536 * 2);
  ushort* Wt2 = (ushort*)alloc(65536 * 2);
  int* cnt = (int*)alloc((size_t)N * 4);                 // reused as fill cursor
  float* isd = (float*)alloc((size_t)N * 4);
  int* row_ptr = (int*)alloc((size_t)(N + 1) * 4);
  int nb = (N + 1023) / 1024;
  int* bsum = (int*)alloc((size_t)nb * 4);
  int2* edat = (int2*)alloc((size_t)E * 8);              // packed (src, nrm)

  float* z1 = (float*)d_out;
  float* z2 = (float*)d_out + (size_t)N * C_DIM;

  // conversions
  int n4 = N * C_DIM / 4;
  k_cvt_x<<<(n4 + 255) / 256, 256, 0, stream>>>(x, xb, n4);
  k_cvt_w<<<256, 256, 0, stream>>>(W1, W2, Wt1, Wt2);

  // CSR build (shared by both layers)
  (void)hipMemsetAsync(cnt, 0, (size_t)N * 4, stream);
  k_count<<<(E + 255) / 256, 256, 0, stream>>>(col, E, cnt);
  k_scan1<<<nb, 1024, 0, stream>>>(cnt, row_ptr, bsum, N);
  k_scan2<<<1, 1024, 0, stream>>>(bsum, nb);
  k_scan3<<<nb, 1024, 0, stream>>>(row_ptr, bsum, N, E);
  k_isd<<<(N + 255) / 256, 256, 0, stream>>>(cnt, isd, N);  // zeroes cnt -> cursor
  k_fill<<<(E + 255) / 256, 256, 0, stream>>>(row, col, E, row_ptr, cnt, isd, edat);

  dim3 ggrid((N + 127) / 128, 2);
  int agg_blocks = (N + 3) / 4;

  // layer 1
  k_gemm_bf16<<<ggrid, 256, 0, stream>>>(xb, Wt1, xwb, N);
  k_agg_ln<<<agg_blocks, 256, 0, stream>>>(xwb, edat, row_ptr, isd, b1, gamma, beta, z1, xb, N);
  // layer 2 (xb now holds z1 in bf16)
  k_gemm_bf16<<<ggrid, 256, 0, stream>>>(xb, Wt2, xwb, N);
  k_agg_ln<<<agg_blocks, 256, 0, stream>>>(xwb, edat, row_ptr, isd, b2, gamma, beta, z2, nullptr, N);
}